// Round 4
// baseline (474.946 us; speedup 1.0000x reference)
//
#include <hip/hip_runtime.h>
#include <hip/hip_fp16.h>

// Segment-sum with gather: out[csr[e]] += x[ptrs[e]], csr sorted.
// E = 33,554,432 edges; N_IN = N_OUT = 4,194,304.
//
// R4: windowing (r3) cut fetch bytes 2.2x but ran SLOWER -> the limit is the
// random-gather REQUEST rate (~89G line-touches/s, per-CU miss-concurrency
// x latency), not bytes. Revert to single pass over f16 x (8 MB). Probe the
// per-wave MLP axis: VPT=32 as two pipelined 16-edge half-batches, all 32
// gathers issued before consumption. Accumulator carried across the halves
// (fewer boundary atomics). XCD swizzle kept for atomic write locality.

typedef int   v4i __attribute__((ext_vector_type(4)));
typedef float v4f __attribute__((ext_vector_type(4)));

#define VPT   32
#define HALF_VPT 16
#define BLOCK 256
#define NXCD  8

__global__ __launch_bounds__(BLOCK) void x_to_f16_kernel(
    const float* __restrict__ x, __half* __restrict__ xh)
{
    const int i = (blockIdx.x * BLOCK + threadIdx.x) * 8;
    const v4f* src = reinterpret_cast<const v4f*>(x + i);
    v4f a = __builtin_nontemporal_load(src);
    v4f b = __builtin_nontemporal_load(src + 1);
    union { __half h[8]; v4i v; } u;
#pragma unroll
    for (int k = 0; k < 4; ++k) u.h[k]     = __float2half(a[k]);
#pragma unroll
    for (int k = 0; k < 4; ++k) u.h[4 + k] = __float2half(b[k]);
    *reinterpret_cast<v4i*>(xh + i) = u.v;
}

__global__ __launch_bounds__(BLOCK) void seg_sum_f16_kernel(
    const __half* __restrict__ xh,
    const int*    __restrict__ ptrs,
    const int*    __restrict__ csr,
    float*        __restrict__ out)
{
    // XCD-aware swizzle: give each XCD a contiguous 1/8 of the edge list so
    // atomic out-lines stay XCD-local. Bijective (gridDim.x % 8 == 0).
    const int nb    = gridDim.x;
    const int bid   = blockIdx.x;
    const int chunk = (bid & (NXCD - 1)) * (nb / NXCD) + (bid / NXCD);

    const long long base = ((long long)chunk * BLOCK + threadIdx.x) * VPT;

    const v4i* p4 = reinterpret_cast<const v4i*>(ptrs + base);
    const v4i* c4 = reinterpret_cast<const v4i*>(csr  + base);
    const unsigned short* __restrict__ xu =
        reinterpret_cast<const unsigned short*>(xh);

    // Load all 32 ptr/csr values (8x int4, nt: use-once streams).
    v4i p[VPT / 4], c[VPT / 4];
#pragma unroll
    for (int q = 0; q < VPT / 4; ++q) {
        p[q] = __builtin_nontemporal_load(p4 + q);
        c[q] = __builtin_nontemporal_load(c4 + q);
    }

    int pi[VPT], ci[VPT];
#pragma unroll
    for (int q = 0; q < VPT / 4; ++q) {
#pragma unroll
        for (int k = 0; k < 4; ++k) {
            pi[4 * q + k] = p[q][k];
            ci[4 * q + k] = c[q][k];
        }
    }

    // Issue ALL 32 gathers before any consumption (max per-wave MLP).
    unsigned short h[VPT];
#pragma unroll
    for (int j = 0; j < VPT; ++j) h[j] = xu[pi[j]];

    // Run-length accumulate over sorted csr; one atomic per run.
    float acc = __half2float(__ushort_as_half(h[0]));
    int   cur = ci[0];
#pragma unroll
    for (int j = 1; j < VPT; ++j) {
        const float vj = __half2float(__ushort_as_half(h[j]));
        if (ci[j] == cur) {
            acc += vj;
        } else {
            atomicAdd(&out[cur], acc);
            cur = ci[j];
            acc = vj;
        }
    }
    atomicAdd(&out[cur], acc);
}

// Fallback (f32 gather, VPT=16) if workspace is too small for the f16 copy.
__global__ __launch_bounds__(BLOCK) void seg_sum_f32_kernel(
    const float* __restrict__ x,
    const int*   __restrict__ ptrs,
    const int*   __restrict__ csr,
    float*       __restrict__ out)
{
    const long long tid  = (long long)blockIdx.x * BLOCK + threadIdx.x;
    const long long base = tid * HALF_VPT;
    const v4i* p4 = reinterpret_cast<const v4i*>(ptrs + base);
    const v4i* c4 = reinterpret_cast<const v4i*>(csr  + base);
    v4i p[HALF_VPT / 4], c[HALF_VPT / 4];
#pragma unroll
    for (int q = 0; q < HALF_VPT / 4; ++q) {
        p[q] = __builtin_nontemporal_load(p4 + q);
        c[q] = __builtin_nontemporal_load(c4 + q);
    }
    int pi[HALF_VPT], ci[HALF_VPT];
#pragma unroll
    for (int q = 0; q < HALF_VPT / 4; ++q) {
#pragma unroll
        for (int k = 0; k < 4; ++k) { pi[4*q+k] = p[q][k]; ci[4*q+k] = c[q][k]; }
    }
    float v[HALF_VPT];
#pragma unroll
    for (int j = 0; j < HALF_VPT; ++j) v[j] = x[pi[j]];
    float acc = v[0];
    int   cur = ci[0];
#pragma unroll
    for (int j = 1; j < HALF_VPT; ++j) {
        if (ci[j] == cur) { acc += v[j]; }
        else { atomicAdd(&out[cur], acc); cur = ci[j]; acc = v[j]; }
    }
    atomicAdd(&out[cur], acc);
}

extern "C" void kernel_launch(void* const* d_in, const int* in_sizes, int n_in,
                              void* d_out, int out_size, void* d_ws, size_t ws_size,
                              hipStream_t stream) {
    const float* x    = (const float*)d_in[0];
    const int*   ptrs = (const int*)d_in[1];
    const int*   csr  = (const int*)d_in[2];
    float*       out  = (float*)d_out;

    const int n_in_elems = in_sizes[0];       // 4,194,304
    const int e          = in_sizes[1];       // 33,554,432

    // Empty segments must be 0 and d_out is poisoned: zero every call.
    hipMemsetAsync(d_out, 0, (size_t)out_size * sizeof(float), stream);

    const size_t xh_bytes = (size_t)n_in_elems * sizeof(__half);
    const int grid32 = e / (VPT * BLOCK);     // 4,096 (multiple of 8)
    if (ws_size >= xh_bytes && (grid32 % NXCD) == 0) {
        __half* xh = (__half*)d_ws;
        x_to_f16_kernel<<<n_in_elems / (BLOCK * 8), BLOCK, 0, stream>>>(x, xh);
        seg_sum_f16_kernel<<<grid32, BLOCK, 0, stream>>>(xh, ptrs, csr, out);
    } else {
        seg_sum_f32_kernel<<<e / (HALF_VPT * BLOCK), BLOCK, 0, stream>>>(
            x, ptrs, csr, out);
    }
}

// Round 5
// 392.036 us; speedup vs baseline: 1.2115x; 1.2115x over previous
//
#include <hip/hip_runtime.h>
#include <hip/hip_fp16.h>

// Segment-sum with gather: out[csr[e]] += x[ptrs[e]], csr sorted.
// E = 33,554,432 edges; N_IN = N_OUT = 4,194,304.
//
// R5: revert to the r2 optimum. Established model: runtime is capped by the
// random line-REQUEST rate (~89G touches/s ~= 0.145 lines/cy/CU), not bytes
// (r3: bytes/2.2 -> slower) and not per-wave MLP (r4: VPT=32 -> slower).
// Floor = 33.5M gathers / 89G/s ~= 375 us = r2's measured kernel time.
// Config: VPT=16, BLOCK=256, 2M threads, f16 x-copy (keeps us off the byte
// ceiling), nt stream loads, run-length atomics. Out-zeroing fused into the
// convert kernel (saves the memset node).

typedef int   v4i __attribute__((ext_vector_type(4)));
typedef float v4f __attribute__((ext_vector_type(4)));

#define VPT   16
#define BLOCK 256

// Converts x -> f16 (xh) and zeroes out[] in the same pass.
// n_in == n_out == 4,194,304; each thread handles 8 of each.
__global__ __launch_bounds__(BLOCK) void prep_kernel(
    const float* __restrict__ x, __half* __restrict__ xh,
    float* __restrict__ out)
{
    const int i = (blockIdx.x * BLOCK + threadIdx.x) * 8;
    const v4f* src = reinterpret_cast<const v4f*>(x + i);
    v4f a = __builtin_nontemporal_load(src);
    v4f b = __builtin_nontemporal_load(src + 1);
    union { __half h[8]; v4i v; } u;
#pragma unroll
    for (int k = 0; k < 4; ++k) u.h[k]     = __float2half(a[k]);
#pragma unroll
    for (int k = 0; k < 4; ++k) u.h[4 + k] = __float2half(b[k]);
    *reinterpret_cast<v4i*>(xh + i) = u.v;   // keep in cache for gather kernel

    v4f z = {0.0f, 0.0f, 0.0f, 0.0f};
    v4f* o = reinterpret_cast<v4f*>(out + i);
    __builtin_nontemporal_store(z, o);
    __builtin_nontemporal_store(z, o + 1);
}

__global__ __launch_bounds__(BLOCK) void seg_sum_f16_kernel(
    const __half* __restrict__ xh,
    const int*    __restrict__ ptrs,
    const int*    __restrict__ csr,
    float*        __restrict__ out)
{
    const long long tid  = (long long)blockIdx.x * BLOCK + threadIdx.x;
    const long long base = tid * VPT;

    const v4i* p4 = reinterpret_cast<const v4i*>(ptrs + base);
    const v4i* c4 = reinterpret_cast<const v4i*>(csr  + base);

    v4i p[VPT / 4], c[VPT / 4];
#pragma unroll
    for (int q = 0; q < VPT / 4; ++q) {
        p[q] = __builtin_nontemporal_load(p4 + q);  // use-once streams
        c[q] = __builtin_nontemporal_load(c4 + q);
    }

    int pi[VPT], ci[VPT];
#pragma unroll
    for (int q = 0; q < VPT / 4; ++q) {
#pragma unroll
        for (int k = 0; k < 4; ++k) {
            pi[4 * q + k] = p[q][k];
            ci[4 * q + k] = c[q][k];
        }
    }

    // Issue all 16 gathers up-front (independent -> MLP latency hiding).
    float v[VPT];
#pragma unroll
    for (int j = 0; j < VPT; ++j) v[j] = __half2float(xh[pi[j]]);

    // Run-length accumulate over sorted csr; one atomic per run.
    float acc = v[0];
    int   cur = ci[0];
#pragma unroll
    for (int j = 1; j < VPT; ++j) {
        if (ci[j] == cur) {
            acc += v[j];
        } else {
            atomicAdd(&out[cur], acc);
            cur = ci[j];
            acc = v[j];
        }
    }
    atomicAdd(&out[cur], acc);
}

// Fallback (f32 gather) if workspace is too small for the f16 copy.
__global__ __launch_bounds__(BLOCK) void seg_sum_f32_kernel(
    const float* __restrict__ x,
    const int*   __restrict__ ptrs,
    const int*   __restrict__ csr,
    float*       __restrict__ out)
{
    const long long tid  = (long long)blockIdx.x * BLOCK + threadIdx.x;
    const long long base = tid * VPT;
    const v4i* p4 = reinterpret_cast<const v4i*>(ptrs + base);
    const v4i* c4 = reinterpret_cast<const v4i*>(csr  + base);
    v4i p[VPT / 4], c[VPT / 4];
#pragma unroll
    for (int q = 0; q < VPT / 4; ++q) {
        p[q] = __builtin_nontemporal_load(p4 + q);
        c[q] = __builtin_nontemporal_load(c4 + q);
    }
    int pi[VPT], ci[VPT];
#pragma unroll
    for (int q = 0; q < VPT / 4; ++q) {
#pragma unroll
        for (int k = 0; k < 4; ++k) { pi[4*q+k] = p[q][k]; ci[4*q+k] = c[q][k]; }
    }
    float v[VPT];
#pragma unroll
    for (int j = 0; j < VPT; ++j) v[j] = x[pi[j]];
    float acc = v[0];
    int   cur = ci[0];
#pragma unroll
    for (int j = 1; j < VPT; ++j) {
        if (ci[j] == cur) { acc += v[j]; }
        else { atomicAdd(&out[cur], acc); cur = ci[j]; acc = v[j]; }
    }
    atomicAdd(&out[cur], acc);
}

extern "C" void kernel_launch(void* const* d_in, const int* in_sizes, int n_in,
                              void* d_out, int out_size, void* d_ws, size_t ws_size,
                              hipStream_t stream) {
    const float* x    = (const float*)d_in[0];
    const int*   ptrs = (const int*)d_in[1];
    const int*   csr  = (const int*)d_in[2];
    float*       out  = (float*)d_out;

    const int n_in_elems = in_sizes[0];       // 4,194,304
    const int e          = in_sizes[1];       // 33,554,432
    const int grid       = e / (VPT * BLOCK); // 8,192 blocks

    const size_t xh_bytes = (size_t)n_in_elems * sizeof(__half);
    if (ws_size >= xh_bytes && n_in_elems == out_size) {
        __half* xh = (__half*)d_ws;
        // Fused: x->f16 convert + out zeroing (out poisoned by harness).
        prep_kernel<<<n_in_elems / (BLOCK * 8), BLOCK, 0, stream>>>(x, xh, out);
        seg_sum_f16_kernel<<<grid, BLOCK, 0, stream>>>(xh, ptrs, csr, out);
    } else {
        hipMemsetAsync(d_out, 0, (size_t)out_size * sizeof(float), stream);
        seg_sum_f32_kernel<<<grid, BLOCK, 0, stream>>>(x, ptrs, csr, out);
    }
}